// Round 3
// baseline (355.762 us; speedup 1.0000x reference)
//
#include <hip/hip_runtime.h>
#include <math.h>

#define Bn 16
#define Tn 32
#define Wn 128
#define Dn 1024

// ---------------------------------------------------------------------------
// Workspace layout (floats):
//   q  [2][B*D] @ 0       : q_w then q_t (atomically accumulated; memset 0 first)
//   cw [B*T*D]  @ 32768   : word-level context per turn
//   ts [B*T]    @ 557056  : turn scores
// ---------------------------------------------------------------------------

// Kernel 1: q = source @ W for both matrices, i-sliced 8 ways, accumulated
// into the final q with global float atomics (zero-inited via memset).
// grid = 256 (mat[2] x chunk[16] x islice[8]), block = 256.
__global__ __launch_bounds__(256) void qproj_kernel(
    const float* __restrict__ src, const float* __restrict__ Ww,
    const float* __restrict__ Wt, float* __restrict__ q)
{
    __shared__ float s_lds[16 * 132];
    const int tid = threadIdx.x;
    const int mat = blockIdx.x >> 7;
    const int chunk = (blockIdx.x >> 3) & 15;
    const int isl = blockIdx.x & 7;

    // stage source slice: 16 b x 128 i
    #pragma unroll
    for (int k = 0; k < 8; ++k) {
        int idx = k * 256 + tid;
        int bb = idx >> 7, ii = idx & 127;
        s_lds[bb * 132 + ii] = src[bb * Dn + isl * 128 + ii];
    }
    __syncthreads();

    const int lane = tid & 63, wv = tid >> 6;
    const int col4 = chunk * 16 + (lane & 15);
    const int b = (lane >> 4) + 4 * wv;
    const float4* W4 = (const float4*)(mat ? Wt : Ww);
    const float* sb = s_lds + b * 132;

    float4 acc = make_float4(0.f, 0.f, 0.f, 0.f);
    #pragma unroll 8
    for (int ii = 0; ii < 128; ++ii) {
        float4 w4 = W4[(size_t)(isl * 128 + ii) * 256 + col4];
        float s = sb[ii];
        acc.x = fmaf(s, w4.x, acc.x);
        acc.y = fmaf(s, w4.y, acc.y);
        acc.z = fmaf(s, w4.z, acc.z);
        acc.w = fmaf(s, w4.w, acc.w);
    }
    float* dst = q + (size_t)mat * (Bn * Dn) + b * Dn + col4 * 4;
    unsafeAtomicAdd(dst + 0, acc.x);
    unsafeAtomicAdd(dst + 1, acc.y);
    unsafeAtomicAdd(dst + 2, acc.z);
    unsafeAtomicAdd(dst + 3, acc.w);
}

// Kernel 2: per-(b,t) word-level attention, online softmax, single pass over
// memory_bank with software-pipelined row prefetch. grid = 512, block = 1024.
__global__ __launch_bounds__(1024) void word_attn_kernel(
    const float* __restrict__ mem, const float* __restrict__ q,
    const int* __restrict__ lens, const int* __restrict__ turns,
    float* __restrict__ cw, float* __restrict__ ts)
{
    const int bt = blockIdx.x;
    const int b = bt >> 5, t = bt & 31;
    if (t >= turns[b]) return;            // masked turn: never consumed downstream
    const int len = lens[bt];

    const int tid = threadIdx.x, lane = tid & 63, wv = tid >> 6;   // wv in 0..15
    const float* rowb = mem + (size_t)bt * (Wn * Dn);

    // q_w fragment: lane holds d = c*256 + lane*4 + j (c in 0..3, j in 0..3)
    const float4* qa = (const float4*)(q + b * Dn);
    float4 qf[4];
    #pragma unroll
    for (int c = 0; c < 4; ++c) qf[c] = qa[c * 64 + lane];

    float m = -INFINITY, l = 0.f;
    float4 acc[4];
    #pragma unroll
    for (int c = 0; c < 4; ++c) acc[c] = make_float4(0.f, 0.f, 0.f, 0.f);

    int w = wv;
    float4 x[4];
    if (w < len) {
        const float4* r4 = (const float4*)(rowb + (size_t)w * Dn);
        #pragma unroll
        for (int c = 0; c < 4; ++c) x[c] = r4[c * 64 + lane];
    }
    while (w < len) {
        const int wn = w + 16;
        float4 xn[4];
        if (wn < len) {                   // wave-uniform branch; prefetch next row
            const float4* r4 = (const float4*)(rowb + (size_t)wn * Dn);
            #pragma unroll
            for (int c = 0; c < 4; ++c) xn[c] = r4[c * 64 + lane];
        }
        float s = 0.f;
        #pragma unroll
        for (int c = 0; c < 4; ++c) {
            s = fmaf(qf[c].x, x[c].x, s);
            s = fmaf(qf[c].y, x[c].y, s);
            s = fmaf(qf[c].z, x[c].z, s);
            s = fmaf(qf[c].w, x[c].w, s);
        }
        #pragma unroll
        for (int off = 32; off >= 1; off >>= 1) s += __shfl_xor(s, off, 64);

        float mn = fmaxf(m, s);
        float sc = (m == -INFINITY) ? 0.f : __expf(m - mn);
        float p = __expf(s - mn);
        l = l * sc + p;
        #pragma unroll
        for (int c = 0; c < 4; ++c) {
            acc[c].x = fmaf(acc[c].x, sc, p * x[c].x);
            acc[c].y = fmaf(acc[c].y, sc, p * x[c].y);
            acc[c].z = fmaf(acc[c].z, sc, p * x[c].z);
            acc[c].w = fmaf(acc[c].w, sc, p * x[c].w);
        }
        m = mn;
        #pragma unroll
        for (int c = 0; c < 4; ++c) x[c] = xn[c];
        w = wn;
    }

    // merge the 16 per-wave online-softmax states
    __shared__ float m_s[16], l_s[16], red[16];
    __shared__ float acc_s[16 * 1024];
    if (lane == 0) { m_s[wv] = m; l_s[wv] = l; }
    float4* as4 = (float4*)(acc_s + wv * 1024);
    #pragma unroll
    for (int c = 0; c < 4; ++c) as4[c * 64 + lane] = acc[c];
    __syncthreads();

    float M = -INFINITY;
    #pragma unroll
    for (int v = 0; v < 16; ++v) M = fmaxf(M, m_s[v]);
    float L = 0.f, cacc = 0.f;
    #pragma unroll
    for (int v = 0; v < 16; ++v) {
        float f = (l_s[v] > 0.f) ? __expf(m_s[v] - M) : 0.f;
        L += f * l_s[v];
        cacc = fmaf(f, acc_s[v * 1024 + tid], cacc);
    }
    cacc *= 1.f / L;                      // L > 0: len >= 1 guarantees a valid row
    cw[(size_t)bt * Dn + tid] = cacc;

    // turn score: dot(q_t[b], cw[b,t]) across the whole block
    float p = q[Bn * Dn + b * Dn + tid] * cacc;
    #pragma unroll
    for (int off = 32; off >= 1; off >>= 1) p += __shfl_xor(p, off, 64);
    if (lane == 0) red[wv] = p;
    __syncthreads();
    if (tid == 0) {
        float r = 0.f;
        #pragma unroll
        for (int v = 0; v < 16; ++v) r += red[v];
        ts[bt] = r;
    }
}

// Kernel 3: turn-level masked softmax + weighted sum. grid = B, block = 256.
__global__ __launch_bounds__(256) void turn_attn_kernel(
    const float* __restrict__ cw, const float* __restrict__ ts,
    const int* __restrict__ turns, float* __restrict__ out)
{
    const int b = blockIdx.x;
    const int n = turns[b];               // in [1, 32]
    const int tid = threadIdx.x;
    __shared__ float attn[32];
    if (tid < 32) {
        float s = (tid < n) ? ts[b * Tn + tid] : -INFINITY;
        float mm = s;
        #pragma unroll
        for (int off = 16; off >= 1; off >>= 1) mm = fmaxf(mm, __shfl_xor(mm, off, 32));
        float e = (tid < n) ? __expf(s - mm) : 0.f;
        float sum = e;
        #pragma unroll
        for (int off = 16; off >= 1; off >>= 1) sum += __shfl_xor(sum, off, 32);
        attn[tid] = e / sum;
    }
    __syncthreads();
    float4 a = make_float4(0.f, 0.f, 0.f, 0.f);
    for (int tt = 0; tt < n; ++tt) {      // only valid turns -> poisoned cw never read
        float wgt = attn[tt];
        float4 c = ((const float4*)(cw + ((size_t)b * Tn + tt) * Dn))[tid];
        a.x = fmaf(wgt, c.x, a.x);
        a.y = fmaf(wgt, c.y, a.y);
        a.z = fmaf(wgt, c.z, a.z);
        a.w = fmaf(wgt, c.w, a.w);
    }
    ((float4*)(out + b * Dn))[tid] = a;
}

extern "C" void kernel_launch(void* const* d_in, const int* in_sizes, int n_in,
                              void* d_out, int out_size, void* d_ws, size_t ws_size,
                              hipStream_t stream) {
    (void)in_sizes; (void)n_in; (void)out_size; (void)ws_size;
    const float* src   = (const float*)d_in[0];
    const float* mem   = (const float*)d_in[1];
    const int*   lens  = (const int*)d_in[2];
    const int*   turns = (const int*)d_in[3];
    const float* Ww    = (const float*)d_in[4];
    const float* Wt    = (const float*)d_in[5];
    float* ws = (float*)d_ws;
    float* q  = ws;                               // 2 * B*D (q_w, q_t)
    float* cw = ws + 2 * Bn * Dn;                 // B*T*D
    float* ts = cw + (size_t)Bn * Tn * Dn;        // B*T
    float* out = (float*)d_out;

    hipMemsetAsync(q, 0, 2 * Bn * Dn * sizeof(float), stream);
    hipLaunchKernelGGL(qproj_kernel, dim3(256), dim3(256), 0, stream,
                       src, Ww, Wt, q);
    hipLaunchKernelGGL(word_attn_kernel, dim3(Bn * Tn), dim3(1024), 0, stream,
                       mem, q, lens, turns, cw, ts);
    hipLaunchKernelGGL(turn_attn_kernel, dim3(Bn), dim3(256), 0, stream,
                       cw, ts, turns, out);
}